// Round 6
// baseline (146.822 us; speedup 1.0000x reference)
//
#include <hip/hip_runtime.h>
#include <hip/hip_bf16.h>

// LSTM: B=4096, T=200, I=2, H=64, O=2
// grid = 256 blocks x 512 threads (8 waves, 2 waves/SIMD, 1 block/CU).
// Wave w: wq = w&3 -> unit quadrant [16wq,16wq+16); half = w>>2.
// Waves (wq,0) and (wq,1) compute IDENTICAL gate MFMAs (redundant, cheap);
// each activates only 2 of the 4 accumulator rows: regs {2*half, 2*half+1},
// i.e. batch rows grp*4 + 2*half + {0,1}. Two waves per SIMD in different
// activation halves -> one wave's issue hides the other's dep-chain stalls.
// All acc indexing static via wave-uniform branch on `half` (rule #20).
// Activation algebra (gate scales folded into weights: i,f,o: -log2e,
// g: 2*log2e):
//   c' = (c*P + (Eg-1)(1+Ef)) * rcp(P*(1+Ef)),  P = (1+Ei)(Eg+1)
//   h  = (Ec-1) * rcp((1+Eo)(Ec+1)),            Ec = 2^(2*log2e*c)
// => 5 exp + 2 rcp per (row,unit). K-half MFMAs UNchained (VALU add of the
// two halves) to cut the MFMA dep chain.

#define B_ 4096
#define T_ 200

typedef _Float16 half8 __attribute__((ext_vector_type(8)));
typedef float f32x4 __attribute__((ext_vector_type(4)));

#define K1f 1.4426950408889634f   // log2(e)
#define K2f 2.8853900817779268f   // 2*log2(e)

__global__ __launch_bounds__(512) void lstm_kernel(
    const float* __restrict__ x,     // [4096][200][2]
    const float* __restrict__ W_ih,  // [256][2]
    const float* __restrict__ W_hh,  // [256][64]
    const float* __restrict__ b_ih,  // [256]
    const float* __restrict__ b_hh,  // [256]
    const float* __restrict__ W_fc,  // [2][64]
    const float* __restrict__ b_fc,  // [2]
    float* __restrict__ out)         // [4096][2]
{
    __shared__ float xs[16][404];        // x tile (float4-aligned, de-conflicted)
    __shared__ _Float16 h16[2][16][72];  // double-buffered h (pad 64->72)
    __shared__ float wfc[130];           // W_fc (128) + b_fc (2)

    const int tid  = threadIdx.x;
    const int lane = tid & 63;
    const int w    = tid >> 6;      // wave 0..7
    const int wq   = w & 3;         // unit quadrant
    const int half = w >> 2;        // activation half: regs {2h, 2h+1}
    const int cidx = lane & 15;
    const int grp  = lane >> 4;
    const int r0   = blockIdx.x * 16;

    // ---- stage x tile (coalesced float4): 16 rows x 100 float4 ----
    for (int i4 = tid; i4 < 1600; i4 += 512) {
        const int row = i4 / 100;
        const int j4  = i4 - row * 100;
        reinterpret_cast<float4*>(&xs[row][0])[j4] =
            reinterpret_cast<const float4*>(x + (size_t)(r0 + row) * 400)[j4];
    }
    // ---- zero h16 (both buffers incl. pad): 2*16*72 f16 = 1152 dwords ----
    for (int i = tid; i < 1152; i += 512)
        reinterpret_cast<unsigned int*>(&h16[0][0][0])[i] = 0u;
    if (tid < 130) wfc[tid] = (tid < 128) ? W_fc[tid] : b_fc[tid - 128];

    // ---- W_hh B-fragments (f16, PRE-SCALED per gate) + x-proj coeffs ----
    // B-frag layout for mfma_f32_16x16x32_f16: lane l -> col = l&15, k = (l>>4)*8 + e
    half8 bfrag[4][2];
    float wi0[4], wi1[4], bs[4];
    const int u = wq * 16 + cidx;          // hidden unit owned by this lane
    #pragma unroll
    for (int m = 0; m < 4; ++m) {          // gate: 0=i,1=f,2=g,3=o (PyTorch order)
        const float sc = (m == 2) ? K2f : -K1f;
        const int g = m * 64 + u;
        wi0[m] = W_ih[g * 2 + 0] * sc;
        wi1[m] = W_ih[g * 2 + 1] * sc;
        bs[m]  = (b_ih[g] + b_hh[g]) * sc;
        #pragma unroll
        for (int kt = 0; kt < 2; ++kt) {
            const float* p = W_hh + g * 64 + kt * 32 + grp * 8;
            const float4 lo = reinterpret_cast<const float4*>(p)[0];
            const float4 hi = reinterpret_cast<const float4*>(p)[1];
            half8 f;
            f[0] = (_Float16)(lo.x * sc); f[1] = (_Float16)(lo.y * sc);
            f[2] = (_Float16)(lo.z * sc); f[3] = (_Float16)(lo.w * sc);
            f[4] = (_Float16)(hi.x * sc); f[5] = (_Float16)(hi.y * sc);
            f[6] = (_Float16)(hi.z * sc); f[7] = (_Float16)(hi.w * sc);
            bfrag[m][kt] = f;
        }
    }

    const int rowA = grp * 4 + 2 * half;    // first batch row this lane activates
    float cstA = 0.f, cstB = 0.f;           // cell states for rows rowA, rowA+1

    __syncthreads();

    // One activation chain: pre-act args already exp2-scaled.
    #define ACT(pi, pf, pg, po, cst, hvout)                                    \
        {                                                                      \
            const float Ei = __builtin_amdgcn_exp2f(pi);                       \
            const float Ef = __builtin_amdgcn_exp2f(pf);                       \
            const float Eg = __builtin_amdgcn_exp2f(pg);                       \
            const float Eo = __builtin_amdgcn_exp2f(po);                       \
            const float fEf = 1.0f + Ef;                                       \
            const float P   = (1.0f + Ei) * (Eg + 1.0f);                       \
            const float r1  = __builtin_amdgcn_rcpf(P * fEf);                  \
            cst = fmaf(cst, P, (Eg - 1.0f) * fEf) * r1;                        \
            const float Ec = __builtin_amdgcn_exp2f(fminf(K2f * cst, 60.0f));  \
            const float r2 = __builtin_amdgcn_rcpf((1.0f + Eo) * (Ec + 1.0f)); \
            hvout = (Ec - 1.0f) * r2;                                          \
        }

    for (int t = 0; t < T_; ++t) {
        const int rd = t & 1;
        const _Float16* hb = &h16[rd][0][0];
        // A-frag: lane l -> A[row=l&15][k=(l>>4)*8+e] (+32 for second k-tile)
        const half8 a0 = *reinterpret_cast<const half8*>(hb + cidx * 72 + grp * 8);
        const half8 a1 = *reinterpret_cast<const half8*>(hb + cidx * 72 + 32 + grp * 8);

        const float2 xvA = *reinterpret_cast<const float2*>(&xs[rowA][2 * t]);
        const float2 xvB = *reinterpret_cast<const float2*>(&xs[rowA + 1][2 * t]);

        // C-init: proj for this wave's 2 rows in the right (static) slots.
        f32x4 Cin[4];
        float pA[4], pB[4];
        #pragma unroll
        for (int m = 0; m < 4; ++m) {
            pA[m] = fmaf(xvA.y, wi1[m], fmaf(xvA.x, wi0[m], bs[m]));
            pB[m] = fmaf(xvB.y, wi1[m], fmaf(xvB.x, wi0[m], bs[m]));
        }
        if (half == 0) {
            #pragma unroll
            for (int m = 0; m < 4; ++m) Cin[m] = (f32x4){pA[m], pB[m], 0.f, 0.f};
        } else {
            #pragma unroll
            for (int m = 0; m < 4; ++m) Cin[m] = (f32x4){0.f, 0.f, pA[m], pB[m]};
        }

        // UNchained K-half MFMAs; combine only the two needed regs with v_add.
        f32x4 lo[4], hi[4];
        const f32x4 zero = {0.f, 0.f, 0.f, 0.f};
        #pragma unroll
        for (int m = 0; m < 4; ++m) {
            lo[m] = __builtin_amdgcn_mfma_f32_16x16x32_f16(a0, bfrag[m][0], Cin[m], 0, 0, 0);
            hi[m] = __builtin_amdgcn_mfma_f32_16x16x32_f16(a1, bfrag[m][1], zero, 0, 0, 0);
        }

        float hvA, hvB;
        if (half == 0) {
            ACT(lo[0][0] + hi[0][0], lo[1][0] + hi[1][0], lo[2][0] + hi[2][0],
                lo[3][0] + hi[3][0], cstA, hvA);
            ACT(lo[0][1] + hi[0][1], lo[1][1] + hi[1][1], lo[2][1] + hi[2][1],
                lo[3][1] + hi[3][1], cstB, hvB);
        } else {
            ACT(lo[0][2] + hi[0][2], lo[1][2] + hi[1][2], lo[2][2] + hi[2][2],
                lo[3][2] + hi[3][2], cstA, hvA);
            ACT(lo[0][3] + hi[0][3], lo[1][3] + hi[1][3], lo[2][3] + hi[2][3],
                lo[3][3] + hi[3][3], cstB, hvB);
        }

        h16[rd ^ 1][rowA][u]     = (_Float16)hvA;
        h16[rd ^ 1][rowA + 1][u] = (_Float16)hvB;
        __syncthreads();
    }

    // ---- FC epilogue: h_last is in h16[0] (t=199 wrote buffer 0) ----
    if (tid < 32) {
        const int r = tid & 15;
        const int o = tid >> 4;
        float s = wfc[128 + o];
        #pragma unroll
        for (int k = 0; k < 64; ++k)
            s = fmaf(wfc[o * 64 + k], (float)h16[0][r][k], s);
        out[(size_t)(r0 + r) * 2 + o] = s;
    }
}

extern "C" void kernel_launch(void* const* d_in, const int* in_sizes, int n_in,
                              void* d_out, int out_size, void* d_ws, size_t ws_size,
                              hipStream_t stream) {
    const float* x    = (const float*)d_in[0];
    const float* W_ih = (const float*)d_in[1];
    const float* W_hh = (const float*)d_in[2];
    const float* b_ih = (const float*)d_in[3];
    const float* b_hh = (const float*)d_in[4];
    const float* W_fc = (const float*)d_in[5];
    const float* b_fc = (const float*)d_in[6];
    float* out = (float*)d_out;

    lstm_kernel<<<B_ / 16, 512, 0, stream>>>(x, W_ih, W_hh, b_ih, b_hh, W_fc, b_fc, out);
}

// Round 7
// 104.531 us; speedup vs baseline: 1.4046x; 1.4046x over previous
//
#include <hip/hip_runtime.h>
#include <hip/hip_bf16.h>

// LSTM: B=4096, T=200, I=2, H=64, O=2
// grid = 256 blocks x 512 threads (8 waves, 2 waves/SIMD, 1 block/CU).
// Wave w: wq = w&3 -> unit quadrant [16wq,16wq+16); half = w>>2.
// Waves (wq,0) and (wq,1) compute redundant gate MFMAs, but each loads its
// A-fragment from rows ROTATED by 2*half: A'[p] = h[(p+2*half)&15]. Then
// D reg r of group g holds gate row (4g+r+2*half)&15, so BOTH halves extract
// STATIC regs {0,1} for their two batch rows 4g+2*half+{0,1} — branchless,
// no if-conversion (R6 lesson: threadIdx-derived branches if-convert and
// execute both sides). K-half MFMAs chained (TLP hides latency). Next-step
// x-projection computed in the MFMA shadow (software pipeline).
// Activation algebra (gate scales folded into weights: i,f,o: -log2e,
// g: 2*log2e):
//   c' = (c*P + (Eg-1)(1+Ef)) * rcp(P*(1+Ef)),  P = (1+Ei)(Eg+1)
//   h  = (Ec-1) * rcp((1+Eo)(Ec+1)),            Ec = 2^(2*log2e*c)
// => 5 exp + 2 rcp per (row,unit).

#define B_ 4096
#define T_ 200

typedef _Float16 half8 __attribute__((ext_vector_type(8)));
typedef float f32x4 __attribute__((ext_vector_type(4)));

#define K1f 1.4426950408889634f   // log2(e)
#define K2f 2.8853900817779268f   // 2*log2(e)

__global__ __launch_bounds__(512) void lstm_kernel(
    const float* __restrict__ x,     // [4096][200][2]
    const float* __restrict__ W_ih,  // [256][2]
    const float* __restrict__ W_hh,  // [256][64]
    const float* __restrict__ b_ih,  // [256]
    const float* __restrict__ b_hh,  // [256]
    const float* __restrict__ W_fc,  // [2][64]
    const float* __restrict__ b_fc,  // [2]
    float* __restrict__ out)         // [4096][2]
{
    __shared__ float xs[16][404];        // x tile (float4-aligned; 400..403 pad)
    __shared__ _Float16 h16[2][16][72];  // double-buffered h (pad 64->72)
    __shared__ float wfc[130];           // W_fc (128) + b_fc (2)

    const int tid  = threadIdx.x;
    const int lane = tid & 63;
    const int w    = tid >> 6;      // wave 0..7
    const int wq   = w & 3;         // unit quadrant
    const int half = w >> 2;        // row-half selector (via rotation, no branch)
    const int cidx = lane & 15;
    const int grp  = lane >> 4;
    const int r0   = blockIdx.x * 16;

    // ---- stage x tile (coalesced float4): 16 rows x 100 float4 ----
    for (int i4 = tid; i4 < 1600; i4 += 512) {
        const int row = i4 / 100;
        const int j4  = i4 - row * 100;
        reinterpret_cast<float4*>(&xs[row][0])[j4] =
            reinterpret_cast<const float4*>(x + (size_t)(r0 + row) * 400)[j4];
    }
    // ---- zero h16 (both buffers incl. pad): 2*16*72 f16 = 1152 dwords ----
    for (int i = tid; i < 1152; i += 512)
        reinterpret_cast<unsigned int*>(&h16[0][0][0])[i] = 0u;
    if (tid < 130) wfc[tid] = (tid < 128) ? W_fc[tid] : b_fc[tid - 128];

    // ---- W_hh B-fragments (f16, PRE-SCALED per gate) + x-proj coeffs ----
    // B-frag layout for mfma_f32_16x16x32_f16: lane l -> col = l&15, k = (l>>4)*8 + e
    half8 bfrag[4][2];
    float wi0[4], wi1[4], bs[4];
    const int u = wq * 16 + cidx;          // hidden unit owned by this lane
    #pragma unroll
    for (int m = 0; m < 4; ++m) {          // gate: 0=i,1=f,2=g,3=o (PyTorch order)
        const float sc = (m == 2) ? K2f : -K1f;
        const int g = m * 64 + u;
        wi0[m] = W_ih[g * 2 + 0] * sc;
        wi1[m] = W_ih[g * 2 + 1] * sc;
        bs[m]  = (b_ih[g] + b_hh[g]) * sc;
        #pragma unroll
        for (int kt = 0; kt < 2; ++kt) {
            const float* p = W_hh + g * 64 + kt * 32 + grp * 8;
            const float4 lo = reinterpret_cast<const float4*>(p)[0];
            const float4 hi = reinterpret_cast<const float4*>(p)[1];
            half8 f;
            f[0] = (_Float16)(lo.x * sc); f[1] = (_Float16)(lo.y * sc);
            f[2] = (_Float16)(lo.z * sc); f[3] = (_Float16)(lo.w * sc);
            f[4] = (_Float16)(hi.x * sc); f[5] = (_Float16)(hi.y * sc);
            f[6] = (_Float16)(hi.z * sc); f[7] = (_Float16)(hi.w * sc);
            bfrag[m][kt] = f;
        }
    }

    const int arow = (cidx + 2 * half) & 15;  // rotated A-frag source row
    const int rowA = grp * 4 + 2 * half;      // first batch row this lane activates
    float cstA = 0.f, cstB = 0.f;             // cell states for rows rowA, rowA+1

    __syncthreads();

    // One activation chain: pre-act args already exp2-scaled.
    #define ACT(pi, pf, pg, po, cst, hvout)                                    \
        {                                                                      \
            const float Ei = __builtin_amdgcn_exp2f(pi);                       \
            const float Ef = __builtin_amdgcn_exp2f(pf);                       \
            const float Eg = __builtin_amdgcn_exp2f(pg);                       \
            const float Eo = __builtin_amdgcn_exp2f(po);                       \
            const float fEf = 1.0f + Ef;                                       \
            const float P   = (1.0f + Ei) * (Eg + 1.0f);                       \
            const float r1  = __builtin_amdgcn_rcpf(P * fEf);                  \
            cst = fmaf(cst, P, (Eg - 1.0f) * fEf) * r1;                        \
            const float Ec = __builtin_amdgcn_exp2f(fminf(K2f * cst, 60.0f));  \
            const float r2 = __builtin_amdgcn_rcpf((1.0f + Eo) * (Ec + 1.0f)); \
            hvout = (Ec - 1.0f) * r2;                                          \
        }

    // initial x-projection (t = 0)
    float projA[4], projB[4];
    {
        const float2 xvA = *reinterpret_cast<const float2*>(&xs[rowA][0]);
        const float2 xvB = *reinterpret_cast<const float2*>(&xs[rowA + 1][0]);
        #pragma unroll
        for (int m = 0; m < 4; ++m) {
            projA[m] = fmaf(xvA.y, wi1[m], fmaf(xvA.x, wi0[m], bs[m]));
            projB[m] = fmaf(xvB.y, wi1[m], fmaf(xvB.x, wi0[m], bs[m]));
        }
    }

    #pragma unroll 2
    for (int t = 0; t < T_; ++t) {
        const int rd = t & 1;
        const _Float16* hb = &h16[rd][0][0];
        // A-frag: lane l -> A'[row=l&15][k=(l>>4)*8+e], A'[p] = h[(p+2*half)&15]
        const half8 a0 = *reinterpret_cast<const half8*>(hb + arow * 72 + grp * 8);
        const half8 a1 = *reinterpret_cast<const half8*>(hb + arow * 72 + 32 + grp * 8);

        f32x4 acc[4];
        #pragma unroll
        for (int m = 0; m < 4; ++m) {
            // C pre-loaded with proj in the two STATIC slots this wave uses
            f32x4 c = {projA[m], projB[m], projA[m], projB[m]};
            c = __builtin_amdgcn_mfma_f32_16x16x32_f16(a0, bfrag[m][0], c, 0, 0, 0);
            c = __builtin_amdgcn_mfma_f32_16x16x32_f16(a1, bfrag[m][1], c, 0, 0, 0);
            acc[m] = c;
        }

        // ---- next-step x-projection in the MFMA shadow (xs padded: t=199
        //      prefetch reads xs[row][400..401] = pad, result unused) ----
        {
            const float2 xvA = *reinterpret_cast<const float2*>(&xs[rowA][2 * t + 2]);
            const float2 xvB = *reinterpret_cast<const float2*>(&xs[rowA + 1][2 * t + 2]);
            #pragma unroll
            for (int m = 0; m < 4; ++m) {
                projA[m] = fmaf(xvA.y, wi1[m], fmaf(xvA.x, wi0[m], bs[m]));
                projB[m] = fmaf(xvB.y, wi1[m], fmaf(xvB.x, wi0[m], bs[m]));
            }
        }

        // ---- activations: STATIC regs 0,1 = batch rows rowA, rowA+1 ----
        float hvA, hvB;
        ACT(acc[0][0], acc[1][0], acc[2][0], acc[3][0], cstA, hvA);
        ACT(acc[0][1], acc[1][1], acc[2][1], acc[3][1], cstB, hvB);

        h16[rd ^ 1][rowA][u]     = (_Float16)hvA;
        h16[rd ^ 1][rowA + 1][u] = (_Float16)hvB;
        __syncthreads();
    }

    // ---- FC epilogue: h_last is in h16[0] (t=199 wrote buffer 0) ----
    if (tid < 32) {
        const int r = tid & 15;
        const int o = tid >> 4;
        float s = wfc[128 + o];
        #pragma unroll
        for (int k = 0; k < 64; ++k)
            s = fmaf(wfc[o * 64 + k], (float)h16[0][r][k], s);
        out[(size_t)(r0 + r) * 2 + o] = s;
    }
}

extern "C" void kernel_launch(void* const* d_in, const int* in_sizes, int n_in,
                              void* d_out, int out_size, void* d_ws, size_t ws_size,
                              hipStream_t stream) {
    const float* x    = (const float*)d_in[0];
    const float* W_ih = (const float*)d_in[1];
    const float* W_hh = (const float*)d_in[2];
    const float* b_ih = (const float*)d_in[3];
    const float* b_hh = (const float*)d_in[4];
    const float* W_fc = (const float*)d_in[5];
    const float* b_fc = (const float*)d_in[6];
    float* out = (float*)d_out;

    lstm_kernel<<<B_ / 16, 512, 0, stream>>>(x, W_ih, W_hh, b_ih, b_hh, W_fc, b_fc, out);
}